// Round 2
// baseline (2531.117 us; speedup 1.0000x reference)
//
#include <hip/hip_runtime.h>
#include <hip/hip_fp16.h>

#define N_NODES 50000
#define N_EDGES 800000
#define WIN_BITS 7
#define WIN 128
#define NBUK ((N_NODES + WIN - 1) / WIN)   // 391
#define BCAP 4096

typedef _Float16 half8 __attribute__((ext_vector_type(8)));
typedef float floatx4 __attribute__((ext_vector_type(4)));

__device__ inline void cvt8(half8 v, float* f) {
    const __half2* p = (const __half2*)&v;
    float2 f0 = __half22float2(p[0]);
    float2 f1 = __half22float2(p[1]);
    float2 f2 = __half22float2(p[2]);
    float2 f3 = __half22float2(p[3]);
    f[0] = f0.x; f[1] = f0.y; f[2] = f1.x; f[3] = f1.y;
    f[4] = f2.x; f[5] = f2.y; f[6] = f3.x; f[7] = f3.y;
}

// ---------------------------------------------------------------------------
// P0 + wfrag combined. Blocks [0,512): bucket edges by dest window (random
// arrival order within bucket -- this randomness is what makes the LDS-atomic
// aggregation collision-free). Blocks [512,540): W fp32 -> fp16 fragments.
// ---------------------------------------------------------------------------
__global__ __launch_bounds__(256) void p0_wfrag(
        const int* __restrict__ ei, int* __restrict__ gcur,
        unsigned* __restrict__ arena, int E,
        const float* __restrict__ W1, const float* __restrict__ W2,
        const float* __restrict__ W3, const float* __restrict__ W4,
        _Float16* __restrict__ Wf1, _Float16* __restrict__ Wf2,
        _Float16* __restrict__ Wf3, _Float16* __restrict__ Wf4) {
    int tid = threadIdx.x;
    if (blockIdx.x >= 512) {
        int b = blockIdx.x - 512;
        const float* W; _Float16* Wf; int FO; int lb;
        if (b < 8)       { W = W1; Wf = Wf1; FO = 128; lb = b; }
        else if (b < 16) { W = W2; Wf = Wf2; FO = 128; lb = b - 8; }
        else if (b < 24) { W = W3; Wf = Wf3; FO = 128; lb = b - 16; }
        else             { W = W4; Wf = Wf4; FO = 64;  lb = b - 24; }
        int g = lb * 256 + tid;
        if (g >= 16 * FO) return;
        int col = g % FO;
        int sq = g / FO;
        int k0 = sq * 8;
        half8 hv;
        #pragma unroll
        for (int j = 0; j < 8; ++j)
            hv[j] = (_Float16)W[(size_t)(k0 + j) * FO + col];
        *(half8*)&Wf[(size_t)g * 8] = hv;
        return;
    }
    __shared__ int lcnt[NBUK];
    __shared__ int lbase[NBUK];
    int chunk = (E + 511) / 512;
    int e0 = blockIdx.x * chunk;
    int e1 = e0 + chunk; if (e1 > E) e1 = E;
    for (int b = tid; b < NBUK; b += 256) lcnt[b] = 0;
    __syncthreads();
    for (int e = e0 + tid; e < e1; e += 256) {
        int dst = ei[E + e];
        atomicAdd(&lcnt[dst >> WIN_BITS], 1);
    }
    __syncthreads();
    for (int b = tid; b < NBUK; b += 256) {
        lbase[b] = atomicAdd(&gcur[b], lcnt[b]);
        lcnt[b] = 0;
    }
    __syncthreads();
    for (int e = e0 + tid; e < e1; e += 256) {
        int dst = ei[E + e];
        int src = ei[e];
        int b = dst >> WIN_BITS;
        int pos = lbase[b] + atomicAdd(&lcnt[b], 1);
        if (pos < BCAP)
            arena[(size_t)b * BCAP + pos] = ((unsigned)src << WIN_BITS) | (unsigned)(dst & (WIN - 1));
    }
}

// ---------------------------------------------------------------------------
// build_dinv: per-bucket degree histogram -> dinv. No CSR, no scans.
// ---------------------------------------------------------------------------
__global__ __launch_bounds__(256) void build_dinv(
        const unsigned* __restrict__ arena, const int* __restrict__ gcur,
        float* __restrict__ dinv, int n) {
    __shared__ int cnt[WIN];
    int b = blockIdx.x, tid = threadIdx.x;
    if (tid < WIN) cnt[tid] = 0;
    __syncthreads();
    int m = gcur[b]; if (m > BCAP) m = BCAP;
    const unsigned* a = arena + (size_t)b * BCAP;
    for (int i = tid; i < m; i += 256) atomicAdd(&cnt[a[i] & (WIN - 1)], 1);
    __syncthreads();
    int base = b << WIN_BITS;
    if (tid < WIN && base + tid < n)
        dinv[base + tid] = rsqrtf((float)(cnt[tid] + 1));
}

// ---------------------------------------------------------------------------
// MFMA GEMM (layer 1, fp32 input), LDS-free: W-fragments from global.
// ---------------------------------------------------------------------------
__global__ __launch_bounds__(256) void gemm_mfma_kernel(
        const float* __restrict__ x, const _Float16* __restrict__ Wfrag,
        const float* __restrict__ dinv, __half* __restrict__ h, int n) {
    constexpr int FO = 128;
    constexpr int NT = FO / 16;
    int tid = threadIdx.x;
    int ln = tid & 15;
    int q  = (tid >> 4) & 3;
    int w  = tid >> 6;
    int node = blockIdx.x * 64 + w * 16 + ln;
    int nodec = node < n ? node : n - 1;
    const float* xrow = x + (size_t)nodec * 128;

    floatx4 acc[NT];
    #pragma unroll
    for (int t = 0; t < NT; ++t) acc[t] = (floatx4){0.f, 0.f, 0.f, 0.f};

    #pragma unroll
    for (int s = 0; s < 4; ++s) {
        const float* xp = xrow + s * 32 + q * 8;
        float4 a0 = *(const float4*)xp;
        float4 a1 = *(const float4*)(xp + 4);
        half8 xf;
        xf[0] = (_Float16)a0.x; xf[1] = (_Float16)a0.y;
        xf[2] = (_Float16)a0.z; xf[3] = (_Float16)a0.w;
        xf[4] = (_Float16)a1.x; xf[5] = (_Float16)a1.y;
        xf[6] = (_Float16)a1.z; xf[7] = (_Float16)a1.w;
        int sq = s * 4 + q;
        #pragma unroll
        for (int t = 0; t < NT; ++t) {
            half8 wf = *(const half8*)&Wfrag[(size_t)(sq * FO + t * 16 + ln) * 8];
            acc[t] = __builtin_amdgcn_mfma_f32_16x16x32_f16(wf, xf, acc[t], 0, 0, 0);
        }
    }

    if (node < n) {
        float dv = dinv[node];
        __half* hrow = h + (size_t)node * FO;
        #pragma unroll
        for (int t = 0; t < NT; ++t) {
            __half2 p[2];
            p[0] = __float22half2_rn(make_float2(acc[t][0] * dv, acc[t][1] * dv));
            p[1] = __float22half2_rn(make_float2(acc[t][2] * dv, acc[t][3] * dv));
            *(uint2*)&hrow[t * 16 + q * 4] = *(const uint2*)p;
        }
    }
}

// ---------------------------------------------------------------------------
// MFMA GEMM, fp16 input (layers 2-4). Input g = relu(agg*dinv+b) from
// agg_bucket. Output pre-scaled by dinv[node] for the next aggregation.
// ---------------------------------------------------------------------------
template<int FO>
__global__ __launch_bounds__(256) void gemm_h(
        const _Float16* __restrict__ g, const _Float16* __restrict__ Wfrag,
        const float* __restrict__ dinv, __half* __restrict__ h, int n) {
    constexpr int NT = FO / 16;
    int tid = threadIdx.x;
    int ln = tid & 15;
    int q  = (tid >> 4) & 3;
    int w  = tid >> 6;
    int node = blockIdx.x * 64 + w * 16 + ln;
    int nodec = node < n ? node : n - 1;
    const _Float16* grow = g + (size_t)nodec * 128;

    floatx4 acc[NT];
    #pragma unroll
    for (int t = 0; t < NT; ++t) acc[t] = (floatx4){0.f, 0.f, 0.f, 0.f};

    #pragma unroll
    for (int s = 0; s < 4; ++s) {
        half8 xf = *(const half8*)&grow[s * 32 + q * 8];
        int sq = s * 4 + q;
        #pragma unroll
        for (int t = 0; t < NT; ++t) {
            half8 wf = *(const half8*)&Wfrag[(size_t)(sq * FO + t * 16 + ln) * 8];
            acc[t] = __builtin_amdgcn_mfma_f32_16x16x32_f16(wf, xf, acc[t], 0, 0, 0);
        }
    }

    if (node < n) {
        float dv = dinv[node];
        __half* hrow = h + (size_t)node * FO;
        #pragma unroll
        for (int t = 0; t < NT; ++t) {
            __half2 p[2];
            p[0] = __float22half2_rn(make_float2(acc[t][0] * dv, acc[t][1] * dv));
            p[1] = __float22half2_rn(make_float2(acc[t][2] * dv, acc[t][3] * dv));
            *(uint2*)&hrow[t * 16 + q * 4] = *(const uint2*)p;
        }
    }
}

// ---------------------------------------------------------------------------
// agg_bucket: edge-parallel scatter-aggregation. Block = (bucket of 128 dst
// nodes) x (64-feature chunk). LDS fp32 accumulator [128][65] (33 KB -> 4
// blocks/CU). Streams the bucket's edges in random arena order: per wave-
// instruction 8 edges x (8 lanes x 16 B) gather one 128-B row-chunk each,
// then 8 ds_add_f32 per lane into the tile. No dependent per-node chains ->
// throughput-bound, not latency-bound. Stride 65: bank = dl + 8*sl + j -> ~2-way.
// Self-loop rows seed the accumulator. Epilogue: *dinv[dst] + bias (+relu).
// ---------------------------------------------------------------------------
template<int FO, bool RELU, bool F32OUT>
__global__ __launch_bounds__(512) void agg_bucket(
        const _Float16* __restrict__ hin, const unsigned* __restrict__ arena,
        const int* __restrict__ gcur, const float* __restrict__ dinv,
        const float* __restrict__ bias, void* __restrict__ outp, int n) {
    constexpr int CH = 64;
    constexpr int STR = CH + 1;
    __shared__ float acc[WIN * STR];          // 33,280 B
    int b = blockIdx.x;
    int ch = blockIdx.y * CH;
    int tid = threadIdx.x;
    int base = b << WIN_BITS;

    int r = tid >> 3, sl = tid & 7;
    // ---- init with self-loop rows (hin rows pre-scaled by dinv[src]) ----
    #pragma unroll
    for (int rr = 0; rr < WIN / 64; ++rr) {
        int row = rr * 64 + r;
        int node = base + row;
        float f[8] = {0.f, 0.f, 0.f, 0.f, 0.f, 0.f, 0.f, 0.f};
        if (node < n)
            cvt8(*(const half8*)&hin[(size_t)node * FO + ch + sl * 8], f);
        float* ar = &acc[row * STR + sl * 8];
        #pragma unroll
        for (int j = 0; j < 8; ++j) ar[j] = f[j];
    }
    __syncthreads();

    // ---- edge-parallel accumulate ----
    int m = gcur[b]; if (m > BCAP) m = BCAP;
    const unsigned* ap = arena + (size_t)b * BCAP;
    int w = tid >> 6;
    int lane = tid & 63;
    int eo = lane >> 3, sl8 = lane & 7;
    const _Float16* hch = hin + ch + sl8 * 8;
    int i = w * 8;
    #pragma unroll 4
    for (; i + 8 <= m; i += 64) {
        unsigned u = ap[i + eo];
        int src = (int)(u >> WIN_BITS);
        int dl = (int)(u & (WIN - 1));
        float f[8];
        cvt8(*(const half8*)&hch[(size_t)src * FO], f);
        float* ar = &acc[dl * STR + sl8 * 8];
        #pragma unroll
        for (int j = 0; j < 8; ++j) atomicAdd(&ar[j], f[j]);
    }
    if (i + eo < m) {
        unsigned u = ap[i + eo];
        int src = (int)(u >> WIN_BITS);
        int dl = (int)(u & (WIN - 1));
        float f[8];
        cvt8(*(const half8*)&hch[(size_t)src * FO], f);
        float* ar = &acc[dl * STR + sl8 * 8];
        #pragma unroll
        for (int j = 0; j < 8; ++j) atomicAdd(&ar[j], f[j]);
    }
    __syncthreads();

    // ---- scale + bias (+relu) + store ----
    float bb[8];
    #pragma unroll
    for (int j = 0; j < 8; ++j) bb[j] = bias[ch + sl * 8 + j];
    #pragma unroll
    for (int rr = 0; rr < WIN / 64; ++rr) {
        int row = rr * 64 + r;
        int node = base + row;
        if (node < n) {
            float dv = dinv[node];
            const float* ar = &acc[row * STR + sl * 8];
            float o[8];
            #pragma unroll
            for (int j = 0; j < 8; ++j) {
                float val = fmaf(ar[j], dv, bb[j]);
                o[j] = RELU ? fmaxf(val, 0.f) : val;
            }
            if constexpr (F32OUT) {
                float* orow = (float*)outp + (size_t)node * FO + ch + sl * 8;
                *(float4*)orow = make_float4(o[0], o[1], o[2], o[3]);
                *(float4*)(orow + 4) = make_float4(o[4], o[5], o[6], o[7]);
            } else {
                __half2 ph[4];
                ph[0] = __float22half2_rn(make_float2(o[0], o[1]));
                ph[1] = __float22half2_rn(make_float2(o[2], o[3]));
                ph[2] = __float22half2_rn(make_float2(o[4], o[5]));
                ph[3] = __float22half2_rn(make_float2(o[6], o[7]));
                *(uint4*)&((__half*)outp)[(size_t)node * FO + ch + sl * 8] = *(const uint4*)ph;
            }
        }
    }
}

// ---------------------------------------------------------------------------

extern "C" void kernel_launch(void* const* d_in, const int* in_sizes, int n_in,
                              void* d_out, int out_size, void* d_ws, size_t ws_size,
                              hipStream_t stream) {
    const float* x  = (const float*)d_in[0];
    const int*   ei = (const int*)  d_in[1];
    const float* W1 = (const float*)d_in[2];
    const float* b1 = (const float*)d_in[3];
    const float* W2 = (const float*)d_in[4];
    const float* b2 = (const float*)d_in[5];
    const float* W3 = (const float*)d_in[6];
    const float* b3 = (const float*)d_in[7];
    const float* W4 = (const float*)d_in[8];
    const float* b4 = (const float*)d_in[9];

    const int N = N_NODES, E = N_EDGES;

    char* p = (char*)d_ws;
    auto carve = [&](size_t bytes) {
        char* q = p;
        p += (bytes + 255) & ~(size_t)255;
        return (void*)q;
    };
    float*     dinv    = (float*)    carve((size_t)N * 4);
    int*       gcur    = (int*)      carve((size_t)NBUK * 4);
    unsigned*  arena   = (unsigned*) carve((size_t)NBUK * BCAP * 4);   // 6.4 MB
    _Float16*  Wf1     = (_Float16*) carve((size_t)16 * 128 * 8 * 2);  // 32 KB
    _Float16*  Wf2     = (_Float16*) carve((size_t)16 * 128 * 8 * 2);
    _Float16*  Wf3     = (_Float16*) carve((size_t)16 * 128 * 8 * 2);
    _Float16*  Wf4     = (_Float16*) carve((size_t)16 * 64 * 8 * 2);   // 16 KB
    __half*    A1      = (__half*)   carve((size_t)N * 128 * 2);
    __half*    A2      = (__half*)   carve((size_t)N * 128 * 2);
    __half*    G       = (__half*)   carve((size_t)N * 128 * 2);

    // ---- graph build + W conversion ----
    hipMemsetAsync(gcur, 0, (size_t)NBUK * 4, stream);
    p0_wfrag<<<540, 256, 0, stream>>>(ei, gcur, arena, E,
                                      W1, W2, W3, W4, Wf1, Wf2, Wf3, Wf4);
    build_dinv<<<NBUK, 256, 0, stream>>>(arena, gcur, dinv, N);

    // ---- layers ----
    const int nb64 = (N + 63) / 64;    // 782

    gemm_mfma_kernel<<<nb64, 256, 0, stream>>>(x, Wf1, dinv, A1, N);

    agg_bucket<128, true, false><<<dim3(NBUK, 2), 512, 0, stream>>>(
        (const _Float16*)A1, arena, gcur, dinv, b1, (void*)G, N);
    gemm_h<128><<<nb64, 256, 0, stream>>>((const _Float16*)G, Wf2, dinv, A2, N);

    agg_bucket<128, true, false><<<dim3(NBUK, 2), 512, 0, stream>>>(
        (const _Float16*)A2, arena, gcur, dinv, b2, (void*)G, N);
    gemm_h<128><<<nb64, 256, 0, stream>>>((const _Float16*)G, Wf3, dinv, A1, N);

    agg_bucket<128, true, false><<<dim3(NBUK, 2), 512, 0, stream>>>(
        (const _Float16*)A1, arena, gcur, dinv, b3, (void*)G, N);
    gemm_h<64><<<nb64, 256, 0, stream>>>((const _Float16*)G, Wf4, dinv, A2, N);

    agg_bucket<64, false, true><<<dim3(NBUK, 1), 512, 0, stream>>>(
        (const _Float16*)A2, arena, gcur, dinv, b4, d_out, N);
}